// Round 1
// baseline (9560.568 us; speedup 1.0000x reference)
//
#include <hip/hip_runtime.h>
#include <hip/hip_bf16.h>
#include <math.h>

// Problem constants (reference: B,T,C,H = 4,2048,2048,16; D = C/H = 128)
#define B_ 4
#define T_ 2048
#define C_ 2048
#define H_ 16
#define D_ 128
#define EPS_ 1e-6f

// ---------------------------------------------------------------------------
// GEMM (B-transposed form): Cm[m][n] = sum_k A[m][k] * Bt[n][k]
// Both operands read along k (contiguous) -> coalesced float4 global loads.
// Tile 128(M) x 64(N) x 32(K); 256 threads; each thread computes 8x4.
// LDS is stored k-major (As[k][m], Bs[k][n]) so fragments are contiguous
// float4 reads (ds_read_b128). Pads (+4) keep 16B alignment and break
// power-of-2 bank strides.
// fp32 vector FMA baseline (no fp32 MFMA exists on CDNA4).
// ---------------------------------------------------------------------------
__global__ __launch_bounds__(256) void gemm_bt(
    const float* __restrict__ A, const float* __restrict__ Bt,
    float* __restrict__ Cm, int M, int N, int K) {
  __shared__ __align__(16) float As[32][132];  // [k][m], 128+4 pad
  __shared__ __align__(16) float Bs[32][68];   // [k][n], 64+4 pad
  const int tid = threadIdx.x;
  const int m0 = blockIdx.y * 128;
  const int n0 = blockIdx.x * 64;
  const int tx = tid & 15;   // n direction (x4)
  const int ty = tid >> 4;   // m direction (x8)
  const int c4 = tid & 7;    // k-quad for staging
  const int r0 = tid >> 3;   // row for staging (0..31)

  float acc[8][4];
  #pragma unroll
  for (int i = 0; i < 8; ++i)
    #pragma unroll
    for (int j = 0; j < 4; ++j) acc[i][j] = 0.f;

  for (int kt = 0; kt < K; kt += 32) {
    __syncthreads();  // protect LDS reuse from previous iteration's readers
    #pragma unroll
    for (int i = 0; i < 4; ++i) {          // stage A: 128 rows x 32 k
      int r = r0 + 32 * i;
      float4 v = *(const float4*)(A + (size_t)(m0 + r) * K + kt + c4 * 4);
      As[c4 * 4 + 0][r] = v.x; As[c4 * 4 + 1][r] = v.y;
      As[c4 * 4 + 2][r] = v.z; As[c4 * 4 + 3][r] = v.w;
    }
    #pragma unroll
    for (int i = 0; i < 2; ++i) {          // stage B: 64 rows x 32 k
      int r = r0 + 32 * i;
      float4 v = *(const float4*)(Bt + (size_t)(n0 + r) * K + kt + c4 * 4);
      Bs[c4 * 4 + 0][r] = v.x; Bs[c4 * 4 + 1][r] = v.y;
      Bs[c4 * 4 + 2][r] = v.z; Bs[c4 * 4 + 3][r] = v.w;
    }
    __syncthreads();
    #pragma unroll
    for (int kk = 0; kk < 32; ++kk) {
      float4 a0 = *(const float4*)&As[kk][ty * 8];
      float4 a1 = *(const float4*)&As[kk][ty * 8 + 4];
      float4 bv = *(const float4*)&Bs[kk][tx * 4];
      float am[8] = {a0.x, a0.y, a0.z, a0.w, a1.x, a1.y, a1.z, a1.w};
      float bn[4] = {bv.x, bv.y, bv.z, bv.w};
      #pragma unroll
      for (int i = 0; i < 8; ++i)
        #pragma unroll
        for (int j = 0; j < 4; ++j)
          acc[i][j] = fmaf(am[i], bn[j], acc[i][j]);
    }
  }
  #pragma unroll
  for (int i = 0; i < 8; ++i) {
    float4 o = make_float4(acc[i][0], acc[i][1], acc[i][2], acc[i][3]);
    *(float4*)(Cm + (size_t)(m0 + ty * 8 + i) * N + n0 + tx * 4) = o;
  }
}

// ---------------------------------------------------------------------------
// Fused per-head RMSNorm + RoPE, in place on the q and k sections of qkv.
// qkv layout: [b][t][s][h][d], s in {0=q,1=k,2=v}. One wave per (b,t,h,s).
// Lane l owns the (d=l, d=l+64) rotate_half pair so the rotation is in-reg.
// ---------------------------------------------------------------------------
__global__ __launch_bounds__(256) void rmsnorm_rope(
    float* __restrict__ qkv, const float* __restrict__ cosb,
    const float* __restrict__ sinb, const float* __restrict__ gq,
    const float* __restrict__ gk) {
  const int lane = threadIdx.x & 63;
  const int wid = threadIdx.x >> 6;
  const long gw = (long)blockIdx.x * 4 + wid;  // global wave id
  const int which = (int)(gw & 1);             // 0=q, 1=k
  const long row = gw >> 1;                    // 0 .. B*T*H-1
  const int h = (int)(row % H_);
  const long bt = row / H_;
  const int t = (int)(bt % T_);

  float* p = qkv + bt * (3 * C_) + (size_t)which * C_ + h * D_;
  float x0 = p[lane];
  float x1 = p[lane + 64];

  float ss = x0 * x0 + x1 * x1;
  #pragma unroll
  for (int m = 1; m < 64; m <<= 1) ss += __shfl_xor(ss, m);
  float nrm = 1.0f / sqrtf(ss * (1.0f / (float)D_) + EPS_);

  const float* g = which ? gk : gq;
  x0 = x0 * nrm * g[lane];
  x1 = x1 * nrm * g[lane + 64];

  const float c0 = cosb[(size_t)t * D_ + lane];
  const float c1 = cosb[(size_t)t * D_ + lane + 64];
  const float s0 = sinb[(size_t)t * D_ + lane];
  const float s1 = sinb[(size_t)t * D_ + lane + 64];
  // rotate_half: rot[d] = d<64 ? -x[d+64] : x[d-64]
  p[lane]      = x0 * c0 - x1 * s0;
  p[lane + 64] = x1 * c1 + x0 * s1;
}

// ---------------------------------------------------------------------------
// Flash-style attention, fp32. Block = 16 q-rows (8 waves x 2 half-wave
// rows), KT=32 K/V tile. K/V staged in LDS with a 16B-quad XOR swizzle
// (quad ^= row&7) so both the score-phase ds_read_b128 (lanes vary row) and
// the PV-phase scalar reads (lanes vary d) are bank-conflict-free.
// Online softmax per half-wave (width-32 shfl reduce).
// LDS: Qs 8K + Ks 16K + Vs 16K + Ps 2K = 42.5 KB -> 3 blocks/CU.
// ---------------------------------------------------------------------------
#define KT_ 32
__global__ __launch_bounds__(512) void attn_fwd(
    const float* __restrict__ qkv, float* __restrict__ y) {
  __shared__ __align__(16) float Qs[16][128];
  __shared__ __align__(16) float Ks[KT_][128];
  __shared__ __align__(16) float Vs[KT_][128];
  __shared__ float Ps[8][2][32];

  const int tid = threadIdx.x;
  const int wave = tid >> 6;
  const int lane = tid & 63;
  const int l2 = lane & 31;
  const int half = lane >> 5;
  const int my_r = wave * 2 + half;  // local q row handled in compute phases

  const int blk = blockIdx.x;
  const int qb = blk % (T_ / 16);
  const int bh = blk / (T_ / 16);
  const int h = bh % H_;
  const int b = bh / H_;
  const int t0 = qb * 16;
  const size_t base = (size_t)b * T_ * (3 * C_);

  // Stage Q tile: 512 float4 by 512 threads (one each)
  {
    int r = tid >> 5, d4 = tid & 31;
    float4 v = *(const float4*)(qkv + base + (size_t)(t0 + r) * (3 * C_) +
                                h * D_ + d4 * 4);
    *(float4*)&Qs[r][d4 * 4] = v;
  }

  float m_run = -INFINITY, l_run = 0.f;
  float acc[4] = {0.f, 0.f, 0.f, 0.f};
  const float inv_sqrt_d = 0.08838834764831845f;  // 1/sqrt(128)

  for (int kt = 0; kt < T_; kt += KT_) {
    __syncthreads();  // previous tile's readers done (also covers Qs, iter 0)
    // Stage K,V: 2048 float4 total, 4 per thread, swizzled LDS quads
    #pragma unroll
    for (int it = 0; it < 4; ++it) {
      int i = tid + it * 512;
      int which = i >> 10;     // 0 = K, 1 = V
      int j = i & 1023;
      int r = j >> 5;          // 0..31
      int d4 = j & 31;         // quad within row
      float4 v = *(const float4*)(qkv + base + (size_t)(kt + r) * (3 * C_) +
                                  (size_t)(which + 1) * C_ + h * D_ + d4 * 4);
      int pq = d4 ^ (r & 7);   // swizzled physical quad
      float* dst = which ? &Vs[r][pq * 4] : &Ks[r][pq * 4];
      *(float4*)dst = v;
    }
    __syncthreads();

    // ---- scores: this half-wave's row vs k = l2 ----
    float s = 0.f;
    #pragma unroll
    for (int q = 0; q < 32; ++q) {
      int pq = q ^ (l2 & 7);
      float4 kv = *(const float4*)&Ks[l2][pq * 4];
      float4 qv = *(const float4*)&Qs[my_r][q * 4];
      s = fmaf(qv.x, kv.x, s);
      s = fmaf(qv.y, kv.y, s);
      s = fmaf(qv.z, kv.z, s);
      s = fmaf(qv.w, kv.w, s);
    }
    s *= inv_sqrt_d;

    // ---- online softmax over this 32-k tile (width-32 reduce) ----
    float mx = s;
    #pragma unroll
    for (int m = 1; m < 32; m <<= 1) mx = fmaxf(mx, __shfl_xor(mx, m, 32));
    float m_new = fmaxf(m_run, mx);
    float pr = __expf(s - m_new);
    float sum = pr;
    #pragma unroll
    for (int m = 1; m < 32; m <<= 1) sum += __shfl_xor(sum, m, 32);
    float scale = __expf(m_run - m_new);  // exp(-inf)=0 on first tile
    l_run = l_run * scale + sum;
    m_run = m_new;
    #pragma unroll
    for (int j = 0; j < 4; ++j) acc[j] *= scale;

    Ps[wave][half][l2] = pr;
    // same-wave LDS write->read across lanes: drain lgkm before reading
    asm volatile("s_waitcnt lgkmcnt(0)" ::: "memory");

    // ---- PV: lane owns d = l2 + 32j of its row ----
    #pragma unroll
    for (int k = 0; k < KT_; ++k) {
      float pk = Ps[wave][half][k];
      #pragma unroll
      for (int j = 0; j < 4; ++j) {
        int d = l2 + 32 * j;
        int phys = (((d >> 2) ^ (k & 7)) << 2) | (d & 3);
        acc[j] = fmaf(pk, Vs[k][phys], acc[j]);
      }
    }
  }

  const float invl = 1.0f / l_run;
  const int trow = t0 + my_r;
  const size_t yb = ((size_t)b * T_ + trow) * C_ + h * D_;
  y[yb + l2]      = acc[0] * invl;
  y[yb + l2 + 32] = acc[1] * invl;
  y[yb + l2 + 64] = acc[2] * invl;
  y[yb + l2 + 96] = acc[3] * invl;
}

// ---------------------------------------------------------------------------
// Launch: qkv GEMM -> fused rmsnorm+rope (in place) -> attention -> proj GEMM
// Workspace: qkv (B*T*3C fp32 = 201.3 MB) + y (B*T*C fp32 = 67.1 MB)
//          = 268435456 bytes required of d_ws.
// ---------------------------------------------------------------------------
extern "C" void kernel_launch(void* const* d_in, const int* in_sizes, int n_in,
                              void* d_out, int out_size, void* d_ws,
                              size_t ws_size, hipStream_t stream) {
  const float* x      = (const float*)d_in[0];  // (B,T,C)
  const float* cosb   = (const float*)d_in[1];  // (T,D)
  const float* sinb   = (const float*)d_in[2];  // (T,D)
  const float* w_qkv  = (const float*)d_in[3];  // (3C,C)
  const float* w_proj = (const float*)d_in[4];  // (C,C)
  const float* g_q    = (const float*)d_in[5];  // (D,)
  const float* g_k    = (const float*)d_in[6];  // (D,)
  float* out = (float*)d_out;                   // (B,T,C)

  float* qkv  = (float*)d_ws;                          // B*T*3C
  float* ybuf = qkv + (size_t)B_ * T_ * 3 * C_;        // B*T*C

  const int M = B_ * T_;  // 8192

  // 1) qkv = x @ w_qkv^T   (M x 3C, K = C)
  gemm_bt<<<dim3((3 * C_) / 64, M / 128), 256, 0, stream>>>(
      x, w_qkv, qkv, M, 3 * C_, C_);

  // 2) RMSNorm + RoPE in place on q,k. One wave per (b,t,h,{q,k}).
  rmsnorm_rope<<<(B_ * T_ * H_ * 2) / 4, 256, 0, stream>>>(
      qkv, cosb, sinb, g_q, g_k);

  // 3) attention -> ybuf in [b][t][h][d] (= [b][t][c]) layout
  attn_fwd<<<B_ * H_ * (T_ / 16), 512, 0, stream>>>(qkv, ybuf);

  // 4) out = ybuf @ w_proj^T  (M x C, K = C)
  gemm_bt<<<dim3(C_ / 64, M / 128), 256, 0, stream>>>(
      ybuf, w_proj, out, M, C_, C_);
}

// Round 2
// 1042.796 us; speedup vs baseline: 9.1682x; 9.1682x over previous
//
#include <hip/hip_runtime.h>
#include <math.h>

// B,T,C,H = 4,2048,2048,16; D=128. fp16-MFMA pipeline, fp32 accumulate.
typedef _Float16 f16;
typedef _Float16 f16x8 __attribute__((ext_vector_type(8)));
typedef _Float16 f16x4 __attribute__((ext_vector_type(4)));
typedef float f32x4 __attribute__((ext_vector_type(4)));

#define MFMA16(a, b, c) __builtin_amdgcn_mfma_f32_16x16x32_f16(a, b, c, 0, 0, 0)

// ---------------------------------------------------------------------------
// f32 -> f16 convert, float4 / half4 vectorized, grid-stride
// ---------------------------------------------------------------------------
__global__ __launch_bounds__(256) void cvt_f16(const float* __restrict__ in,
                                               f16* __restrict__ out, long n4) {
  long stride = (long)gridDim.x * 256;
  for (long i = (long)blockIdx.x * 256 + threadIdx.x; i < n4; i += stride) {
    float4 v = ((const float4*)in)[i];
    f16x4 h = {(f16)v.x, (f16)v.y, (f16)v.z, (f16)v.w};
    ((f16x4*)out)[i] = h;
  }
}

// ---------------------------------------------------------------------------
// f16 MFMA GEMM: C[m][n] = sum_k A[m][k] * Bt[n][k].  BM=BN=128, BK=32.
// 256 thr = 4 waves in 2x2; each wave 64x64 = 4x4 frags of 16x16x32.
// LDS [row][32k] f16: 64B rows naturally stagger 16B-slots -> no swizzle
// needed (slot = (4*row+chunk)%8 is uniform across a wave's frag read).
// ---------------------------------------------------------------------------
template <typename OT>
__global__ __launch_bounds__(256) void gemm_f16(const f16* __restrict__ A,
                                                const f16* __restrict__ Bt,
                                                OT* __restrict__ C, int M,
                                                int N, int K) {
  __shared__ __align__(16) f16 As[128 * 32];
  __shared__ __align__(16) f16 Bs[128 * 32];
  const int tid = threadIdx.x;
  const int l = tid & 63, wid = tid >> 6;
  const int lo = l & 15, hi = l >> 4;
  const int m0 = blockIdx.y * 128, n0 = blockIdx.x * 128;
  const int wm = (wid >> 1) * 64, wn = (wid & 1) * 64;
  const int srow = tid >> 2, sch = tid & 3;  // staging row (0..63), chunk

  f32x4 acc[4][4] = {};

  for (int kt = 0; kt < K; kt += 32) {
    __syncthreads();
    {
      const f16* ga0 = A + (size_t)(m0 + srow) * K + kt + sch * 8;
      const f16* ga1 = A + (size_t)(m0 + srow + 64) * K + kt + sch * 8;
      const f16* gb0 = Bt + (size_t)(n0 + srow) * K + kt + sch * 8;
      const f16* gb1 = Bt + (size_t)(n0 + srow + 64) * K + kt + sch * 8;
      f16x8 a0 = *(const f16x8*)ga0;
      f16x8 a1 = *(const f16x8*)ga1;
      f16x8 b0 = *(const f16x8*)gb0;
      f16x8 b1 = *(const f16x8*)gb1;
      *(f16x8*)&As[srow * 32 + sch * 8] = a0;
      *(f16x8*)&As[(srow + 64) * 32 + sch * 8] = a1;
      *(f16x8*)&Bs[srow * 32 + sch * 8] = b0;
      *(f16x8*)&Bs[(srow + 64) * 32 + sch * 8] = b1;
    }
    __syncthreads();
    f16x8 af[4], bf[4];
#pragma unroll
    for (int i = 0; i < 4; ++i) {
      af[i] = *(const f16x8*)&As[(wm + i * 16 + lo) * 32 + hi * 8];
      bf[i] = *(const f16x8*)&Bs[(wn + i * 16 + lo) * 32 + hi * 8];
    }
#pragma unroll
    for (int i = 0; i < 4; ++i)
#pragma unroll
      for (int j = 0; j < 4; ++j) acc[i][j] = MFMA16(af[i], bf[j], acc[i][j]);
  }
  // C/D frag layout: col = lane&15, row = (lane>>4)*4 + r  (m89-verified)
#pragma unroll
  for (int i = 0; i < 4; ++i)
#pragma unroll
    for (int j = 0; j < 4; ++j)
#pragma unroll
      for (int r = 0; r < 4; ++r) {
        int row = m0 + wm + i * 16 + hi * 4 + r;
        int col = n0 + wn + j * 16 + lo;
        C[(size_t)row * N + col] = (OT)acc[i][j][r];
      }
}

// ---------------------------------------------------------------------------
// Fused RMSNorm + RoPE in place on q,k of qkv_h [bt][3][16][128] (f16).
// One wave per (bt, h, s in {q,k}); lane owns the (d, d+64) rotate pair.
// Math in f32 (cos/sin tables are f32 inputs).
// ---------------------------------------------------------------------------
__global__ __launch_bounds__(256) void rope_f16(f16* __restrict__ qkv,
                                                const float* __restrict__ cosb,
                                                const float* __restrict__ sinb,
                                                const float* __restrict__ gq,
                                                const float* __restrict__ gk) {
  const int lane = threadIdx.x & 63;
  const int wid = threadIdx.x >> 6;
  const long gw = (long)blockIdx.x * 4 + wid;
  const int s = (int)(gw & 1);  // 0=q, 1=k
  const long row = gw >> 1;     // (b*T + t)*H + h
  const int h = (int)(row & 15);
  const long bt = row >> 4;
  const int t = (int)(bt & 2047);

  f16* p = qkv + ((bt * 3 + s) * 16 + h) * 128;
  float x0 = (float)p[lane];
  float x1 = (float)p[lane + 64];

  float ss = x0 * x0 + x1 * x1;
#pragma unroll
  for (int m = 1; m < 64; m <<= 1) ss += __shfl_xor(ss, m);
  float nrm = 1.0f / sqrtf(ss * (1.0f / 128.0f) + 1e-6f);

  const float* g = s ? gk : gq;
  x0 *= nrm * g[lane];
  x1 *= nrm * g[lane + 64];

  const float c0 = cosb[(size_t)t * 128 + lane];
  const float c1 = cosb[(size_t)t * 128 + lane + 64];
  const float s0 = sinb[(size_t)t * 128 + lane];
  const float s1 = sinb[(size_t)t * 128 + lane + 64];
  p[lane] = (f16)(x0 * c0 - x1 * s0);
  p[lane + 64] = (f16)(x1 * c1 + x0 * s1);
}

// ---------------------------------------------------------------------------
// V transpose pre-pass: qkv_h v-section [b][t][h][128] -> vt [b][h][128][t].
// 64t x 128d tile via LDS; gather reads are 2-way (free) with the d-major
// lane mapping; 16B global stores (L2 merges the 4KB-strided lines).
// ---------------------------------------------------------------------------
__global__ __launch_bounds__(256) void transpose_v(const f16* __restrict__ qkv,
                                                   f16* __restrict__ vt) {
  __shared__ f16 Tt[64 * 136];  // padded to 17 chunks -> aligned rows
  const int tid = threadIdx.x;
  const int ti = blockIdx.x & 31;
  const int bh = blockIdx.x >> 5;
  const int h = bh & 15;
  const long b = bh >> 4;
  const long t0 = (long)ti * 64;

#pragma unroll
  for (int it = 0; it < 4; ++it) {
    int i = tid + it * 256;
    int r = i >> 4, ch = i & 15;
    const f16* g = qkv + (((b * 2048 + t0 + r) * 3 + 2) * 16 + h) * 128 + ch * 8;
    *(f16x8*)&Tt[r * 136 + ch * 8] = *(const f16x8*)g;
  }
  __syncthreads();
#pragma unroll
  for (int it = 0; it < 4; ++it) {
    int i = tid + it * 256;
    int d = i & 127, ch = i >> 7;  // lanes span d -> conflict-free gathers
    f16x8 v;
#pragma unroll
    for (int j = 0; j < 8; ++j) v[j] = Tt[(ch * 8 + j) * 136 + d];
    *(f16x8*)&vt[((long)bh * 128 + d) * 2048 + t0 + ch * 8] = v;
  }
}

// ---------------------------------------------------------------------------
// Flash attention, f16 MFMA. Block = 256 thr = 4 waves; each wave owns 16
// q-rows; K-tile = 64 keys. K staged [64k][128d], V^T staged [128d][64k],
// both 16B-chunk XOR-swizzled (chunk ^= row&7) -> frag reads at b128 floor.
// Online softmax in f32; P round-trips through per-wave LDS as f16.
// LDS: 16K (K) + 16K (Vt) + 9K (P) = 41 KB -> 3 blocks/CU.
// ---------------------------------------------------------------------------
__global__ __launch_bounds__(256) void attn_f16(const f16* __restrict__ qkv,
                                                const f16* __restrict__ vt,
                                                f16* __restrict__ y) {
  __shared__ __align__(16) f16 Ks[64 * 128];
  __shared__ __align__(16) f16 Vs[128 * 64];
  __shared__ __align__(16) f16 Pl[4][16 * 72];  // [wave][q][64k], padded row

  const int tid = threadIdx.x;
  const int l = tid & 63, w = tid >> 6;
  const int lo = l & 15, hi = l >> 4;
  const int qi = blockIdx.x & 31;
  const int bh = blockIdx.x >> 5;
  const int h = bh & 15;
  const long b = bh >> 4;
  const long tq0 = (long)qi * 64;
  const long base = b * 2048 * 6144;  // qkv batch base (f16 elems)

  // Q fragments live in registers for the whole kernel (A-operand layout:
  // row = lane&15, k-slots = (lane>>4)*8+j; slot permutation cancels since
  // K-frags use the identical mapping).
  f16x8 qf[4];
  {
    const f16* qrow = qkv + base + (tq0 + w * 16 + lo) * 6144 + h * 128;
#pragma unroll
    for (int dc = 0; dc < 4; ++dc)
      qf[dc] = *(const f16x8*)(qrow + dc * 32 + hi * 8);
  }

  f32x4 acc[8] = {};
  float m_run[4] = {-INFINITY, -INFINITY, -INFINITY, -INFINITY};
  float l_run[4] = {0.f, 0.f, 0.f, 0.f};
  const float isd = 0.08838834764831845f;  // 1/sqrt(128)

  for (int kt = 0; kt < 2048; kt += 64) {
    __syncthreads();
    // stage K tile (rows kt..kt+63, s=1 section)
#pragma unroll
    for (int it = 0; it < 4; ++it) {
      int i = tid + it * 256;
      int r = i >> 4, ch = i & 15;
      const f16* g = qkv + base + (long)(kt + r) * 6144 + 2048 + h * 128 + ch * 8;
      *(f16x8*)&Ks[r * 128 + (ch ^ (r & 7)) * 8] = *(const f16x8*)g;
    }
    // stage V^T tile from vt[b][h][d][kt..]
#pragma unroll
    for (int it = 0; it < 4; ++it) {
      int i = tid + it * 256;
      int d = i >> 3, ch = i & 7;
      const f16* g = vt + ((long)bh * 128 + d) * 2048 + kt + ch * 8;
      *(f16x8*)&Vs[d * 64 + (ch ^ (d & 7)) * 8] = *(const f16x8*)g;
    }
    __syncthreads();

    // ---- S = Q K^T : 16 MFMA (4 key-cols x 4 d-chunks) ----
    f32x4 sa[4] = {};
#pragma unroll
    for (int kc = 0; kc < 4; ++kc) {
#pragma unroll
      for (int dc = 0; dc < 4; ++dc) {
        int krow = kc * 16 + lo;
        int chunk = (dc * 4 + hi) ^ (krow & 7);
        f16x8 kf = *(const f16x8*)&Ks[krow * 128 + chunk * 8];
        sa[kc] = MFMA16(qf[dc], kf, sa[kc]);
      }
    }

    // ---- online softmax (lane holds rows q=hi*4+r, col kc*16+lo) ----
    float p_[4][4], mx[4], sc_[4], rs[4];
#pragma unroll
    for (int r = 0; r < 4; ++r) mx[r] = -INFINITY;
#pragma unroll
    for (int kc = 0; kc < 4; ++kc)
#pragma unroll
      for (int r = 0; r < 4; ++r) {
        p_[kc][r] = sa[kc][r] * isd;
        mx[r] = fmaxf(mx[r], p_[kc][r]);
      }
#pragma unroll
    for (int r = 0; r < 4; ++r) {
#pragma unroll
      for (int mm = 1; mm < 16; mm <<= 1)
        mx[r] = fmaxf(mx[r], __shfl_xor(mx[r], mm));
      float mn = fmaxf(m_run[r], mx[r]);
      sc_[r] = __expf(m_run[r] - mn);
      m_run[r] = mn;
      rs[r] = 0.f;
    }
#pragma unroll
    for (int kc = 0; kc < 4; ++kc)
#pragma unroll
      for (int r = 0; r < 4; ++r) {
        float p = __expf(p_[kc][r] - m_run[r]);
        p_[kc][r] = p;
        rs[r] += p;
      }
#pragma unroll
    for (int r = 0; r < 4; ++r) {
#pragma unroll
      for (int mm = 1; mm < 16; mm <<= 1) rs[r] += __shfl_xor(rs[r], mm);
      l_run[r] = l_run[r] * sc_[r] + rs[r];
    }

    // P -> per-wave LDS (f16), then reload as A-operand fragments
#pragma unroll
    for (int kc = 0; kc < 4; ++kc)
#pragma unroll
      for (int r = 0; r < 4; ++r)
        Pl[w][(hi * 4 + r) * 72 + kc * 16 + lo] = (f16)p_[kc][r];
    asm volatile("s_waitcnt lgkmcnt(0)" ::: "memory");  // cross-lane, same wave

    // rescale O by exp(m_old - m_new)
#pragma unroll
    for (int dg = 0; dg < 8; ++dg)
#pragma unroll
      for (int r = 0; r < 4; ++r) acc[dg][r] *= sc_[r];

    f16x8 pf[2];
#pragma unroll
    for (int kh = 0; kh < 2; ++kh)
      pf[kh] = *(const f16x8*)&Pl[w][lo * 72 + kh * 32 + hi * 8];

    // ---- O += P V : 16 MFMA (8 d-groups x 2 k-halves) ----
#pragma unroll
    for (int dg = 0; dg < 8; ++dg) {
#pragma unroll
      for (int kh = 0; kh < 2; ++kh) {
        int drow = dg * 16 + lo;
        int chunk = (kh * 4 + hi) ^ (drow & 7);
        f16x8 vf = *(const f16x8*)&Vs[drow * 64 + chunk * 8];
        acc[dg] = MFMA16(pf[kh], vf, acc[dg]);
      }
    }
  }

  // epilogue: normalize, store y [b][t][h][d] as f16
#pragma unroll
  for (int r = 0; r < 4; ++r) {
    float inv = 1.0f / l_run[r];
    long t = tq0 + w * 16 + hi * 4 + r;
    f16* yr = y + ((b * 2048 + t) * 16 + h) * 128;
#pragma unroll
    for (int dg = 0; dg < 8; ++dg) yr[dg * 16 + lo] = (f16)(acc[dg][r] * inv);
  }
}

// ---------------------------------------------------------------------------
// ws layout (f16 elems): x_h 16.78M | wqkv_h 12.58M | wproj_h 4.19M |
// qkv_h 50.33M | vt 16.78M | y_h 16.78M  = 224 MB total
// ---------------------------------------------------------------------------
extern "C" void kernel_launch(void* const* d_in, const int* in_sizes, int n_in,
                              void* d_out, int out_size, void* d_ws,
                              size_t ws_size, hipStream_t stream) {
  const float* x = (const float*)d_in[0];
  const float* cosb = (const float*)d_in[1];
  const float* sinb = (const float*)d_in[2];
  const float* w_qkv = (const float*)d_in[3];
  const float* w_proj = (const float*)d_in[4];
  const float* g_q = (const float*)d_in[5];
  const float* g_k = (const float*)d_in[6];
  float* out = (float*)d_out;

  f16* ws = (f16*)d_ws;
  f16* x_h = ws;                       // 16777216
  f16* wqkv_h = x_h + 16777216;        // 12582912
  f16* wproj_h = wqkv_h + 12582912;    // 4194304
  f16* qkv_h = wproj_h + 4194304;      // 50331648
  f16* vt_h = qkv_h + 50331648;        // 16777216
  f16* y_h = vt_h + 16777216;          // 16777216

  cvt_f16<<<2048, 256, 0, stream>>>(x, x_h, 16777216 / 4);
  cvt_f16<<<2048, 256, 0, stream>>>(w_qkv, wqkv_h, 12582912 / 4);
  cvt_f16<<<1024, 256, 0, stream>>>(w_proj, wproj_h, 4194304 / 4);

  // qkv = x @ w_qkv^T : M=8192, N=6144, K=2048
  gemm_f16<f16><<<dim3(48, 64), 256, 0, stream>>>(x_h, wqkv_h, qkv_h, 8192,
                                                  6144, 2048);
  rope_f16<<<65536, 256, 0, stream>>>(qkv_h, cosb, sinb, g_q, g_k);
  transpose_v<<<2048, 256, 0, stream>>>(qkv_h, vt_h);
  attn_f16<<<2048, 256, 0, stream>>>(qkv_h, vt_h, y_h);
  // out = y @ w_proj^T : M=8192, N=2048, K=2048 (f32 out)
  gemm_f16<float><<<dim3(16, 64), 256, 0, stream>>>(y_h, wproj_h, out, 8192,
                                                    2048, 2048);
}

// Round 4
// 796.003 us; speedup vs baseline: 12.0107x; 1.3100x over previous
//
#include <hip/hip_runtime.h>
#include <math.h>

// B,T,C,H = 4,2048,2048,16; D=128. fp16-MFMA pipeline, fp32 accumulate.
typedef _Float16 f16;
typedef _Float16 f16x8 __attribute__((ext_vector_type(8)));
typedef _Float16 f16x4 __attribute__((ext_vector_type(4)));
typedef float f32x4 __attribute__((ext_vector_type(4)));

#define MFMA16(a, b, c) __builtin_amdgcn_mfma_f32_16x16x32_f16(a, b, c, 0, 0, 0)

// async global->LDS, 16B per lane (m97 pattern). LDS dest must be
// wave-uniform base + lane*16 (it is: all call sites use &buf[tid*8]).
__device__ __forceinline__ void gload16(const void* g, void* l) {
  __builtin_amdgcn_global_load_lds(
      (const __attribute__((address_space(1))) unsigned int*)g,
      (__attribute__((address_space(3))) unsigned int*)l, 16, 0, 0);
}

// ---------------------------------------------------------------------------
// f32 -> f16 convert
// ---------------------------------------------------------------------------
__global__ __launch_bounds__(256) void cvt_f16(const float* __restrict__ in,
                                               f16* __restrict__ out, long n4) {
  long stride = (long)gridDim.x * 256;
  for (long i = (long)blockIdx.x * 256 + threadIdx.x; i < n4; i += stride) {
    float4 v = ((const float4*)in)[i];
    f16x4 h = {(f16)v.x, (f16)v.y, (f16)v.z, (f16)v.w};
    ((f16x4*)out)[i] = h;
  }
}

// ---------------------------------------------------------------------------
// f16 MFMA GEMM (m97-style staging): C[m][n] = sum_k A[m][k]*Bt[n][k].
// BM=BN=128, BK=32; 4 waves 2x2, each 64x64 (4x4 frags of 16x16x32).
// Staging via global_load_lds dwordx4: LDS row-major [row][32k], linear in
// tid (dest = base + tid*16B). 2 barriers/iter; 2nd barrier's vmcnt(0)
// drain completes the async loads.
// ---------------------------------------------------------------------------
template <typename OT>
__global__ __launch_bounds__(256) void gemm_f16(const f16* __restrict__ A,
                                                const f16* __restrict__ Bt,
                                                OT* __restrict__ C, int M,
                                                int N, int K) {
  __shared__ __align__(16) f16 As[128 * 32];
  __shared__ __align__(16) f16 Bs[128 * 32];
  const int tid = threadIdx.x;
  const int l = tid & 63, wid = tid >> 6;
  const int lo = l & 15, hi = l >> 4;
  const int m0 = blockIdx.y * 128, n0 = blockIdx.x * 128;
  const int wm = (wid >> 1) * 64, wn = (wid & 1) * 64;
  const int srow = tid >> 2, sch = tid & 3;  // staging row (0..63), 8h-chunk

  f32x4 acc[4][4] = {};

  for (int kt = 0; kt < K; kt += 32) {
    __syncthreads();  // previous iteration's LDS readers done
    gload16(A + (size_t)(m0 + srow) * K + kt + sch * 8, &As[tid * 8]);
    gload16(A + (size_t)(m0 + 64 + srow) * K + kt + sch * 8, &As[2048 + tid * 8]);
    gload16(Bt + (size_t)(n0 + srow) * K + kt + sch * 8, &Bs[tid * 8]);
    gload16(Bt + (size_t)(n0 + 64 + srow) * K + kt + sch * 8, &Bs[2048 + tid * 8]);
    __syncthreads();  // drains vmcnt(0): staged data visible to all
    f16x8 af[4], bf[4];
#pragma unroll
    for (int i = 0; i < 4; ++i) {
      af[i] = *(const f16x8*)&As[(wm + i * 16 + lo) * 32 + hi * 8];
      bf[i] = *(const f16x8*)&Bs[(wn + i * 16 + lo) * 32 + hi * 8];
    }
#pragma unroll
    for (int i = 0; i < 4; ++i)
#pragma unroll
      for (int j = 0; j < 4; ++j) acc[i][j] = MFMA16(af[i], bf[j], acc[i][j]);
  }
  // C/D layout: col = lane&15, row = (lane>>4)*4 + r (m89-verified)
#pragma unroll
  for (int i = 0; i < 4; ++i)
#pragma unroll
    for (int j = 0; j < 4; ++j)
#pragma unroll
      for (int r = 0; r < 4; ++r) {
        int row = m0 + wm + i * 16 + hi * 4 + r;
        int col = n0 + wn + j * 16 + lo;
        C[(size_t)row * N + col] = (OT)acc[i][j][r];
      }
}

// ---------------------------------------------------------------------------
// Fused RMSNorm + RoPE in place on q,k of qkv [bt][3][16][128] (f16).
// ---------------------------------------------------------------------------
__global__ __launch_bounds__(256) void rope_f16(f16* __restrict__ qkv,
                                                const float* __restrict__ cosb,
                                                const float* __restrict__ sinb,
                                                const float* __restrict__ gq,
                                                const float* __restrict__ gk) {
  const int lane = threadIdx.x & 63;
  const int wid = threadIdx.x >> 6;
  const long gw = (long)blockIdx.x * 4 + wid;
  const int s = (int)(gw & 1);
  const long row = gw >> 1;
  const int h = (int)(row & 15);
  const long bt = row >> 4;
  const int t = (int)(bt & 2047);

  f16* p = qkv + ((bt * 3 + s) * 16 + h) * 128;
  float x0 = (float)p[lane];
  float x1 = (float)p[lane + 64];

  float ss = x0 * x0 + x1 * x1;
#pragma unroll
  for (int m = 1; m < 64; m <<= 1) ss += __shfl_xor(ss, m);
  float nrm = 1.0f / sqrtf(ss * (1.0f / 128.0f) + 1e-6f);

  const float* g = s ? gk : gq;
  x0 *= nrm * g[lane];
  x1 *= nrm * g[lane + 64];

  const float c0 = cosb[(size_t)t * 128 + lane];
  const float c1 = cosb[(size_t)t * 128 + lane + 64];
  const float s0 = sinb[(size_t)t * 128 + lane];
  const float s1 = sinb[(size_t)t * 128 + lane + 64];
  p[lane] = (f16)(x0 * c0 - x1 * s0);
  p[lane + 64] = (f16)(x1 * c1 + x0 * s1);
}

// ---------------------------------------------------------------------------
// V transpose pre-pass: v-section [b][t][h][128] -> vt [b][h][128][t].
// ---------------------------------------------------------------------------
__global__ __launch_bounds__(256) void transpose_v(const f16* __restrict__ qkv,
                                                   f16* __restrict__ vt) {
  __shared__ f16 Tt[64 * 136];
  const int tid = threadIdx.x;
  const int ti = blockIdx.x & 31;
  const int bh = blockIdx.x >> 5;
  const int h = bh & 15;
  const long b = bh >> 4;
  const long t0 = (long)ti * 64;

#pragma unroll
  for (int it = 0; it < 4; ++it) {
    int i = tid + it * 256;
    int r = i >> 4, ch = i & 15;
    const f16* g = qkv + (((b * 2048 + t0 + r) * 3 + 2) * 16 + h) * 128 + ch * 8;
    *(f16x8*)&Tt[r * 136 + ch * 8] = *(const f16x8*)g;
  }
  __syncthreads();
#pragma unroll
  for (int it = 0; it < 4; ++it) {
    int i = tid + it * 256;
    int d = i & 127, ch = i >> 7;
    f16x8 v;
#pragma unroll
    for (int j = 0; j < 8; ++j) v[j] = Tt[(ch * 8 + j) * 136 + d];
    *(f16x8*)&vt[((long)bh * 128 + d) * 2048 + t0 + ch * 8] = v;
  }
}

// ---------------------------------------------------------------------------
// Flash attention, swapped-operand form. 4 waves x 32 q-rows = 128 q/block.
// QK^T = mfma(K,Q) -> S^T: lane owns ONE query (col=lane&15); softmax
// reduce = 15 local ops + 2 shfl_xor. PV = mfma(V^T, P) -> O^T.
// K/V double-buffered in LDS via global_load_lds w16 with pre-swizzled
// global source addresses (16B-slot XOR by row&7 -> balanced b128 reads).
// P exchanged through a small swizzled per-wave LDS scratch (b64 w/b128 r).
// One __syncthreads per tile (its vmcnt(0) drain completes async staging).
// LDS: Ks 2x16K + Vs 2x16K + Pl 16K = 80 KB -> 2 blocks/CU (VGPR-matched).
// ---------------------------------------------------------------------------
__global__ __launch_bounds__(256, 2) void attn_f16(const f16* __restrict__ qkv,
                                                   const f16* __restrict__ vt,
                                                   f16* __restrict__ y) {
  __shared__ __align__(16) f16 Ks[2][64 * 128];
  __shared__ __align__(16) f16 Vs[2][128 * 64];
  __shared__ __align__(16) f16 Pl[4][2][16 * 64];

  const int tid = threadIdx.x;
  const int l = tid & 63, w = tid >> 6;
  const int lo = l & 15, hi = l >> 4;
  const int qi = blockIdx.x & 15;
  const int bh = blockIdx.x >> 4;
  const int h = bh & 15;
  const long b = bh >> 4;
  const long tq0 = (long)qi * 128;
  const long base = b * 2048 * 6144;
  const float isd = 0.08838834764831845f;  // 1/sqrt(128)

  // staging address components (pre-swizzled global source, linear LDS dest)
  const int krow = tid >> 4;                      // + i*16
  const int kch = (tid & 15) ^ (krow & 7);        // row&7 == krow&7 (i*16 even)
  const int vd = tid >> 3;                        // + i*32
  const int vch = (tid & 7) ^ (vd & 7);           // d&7 == vd&7 (i*32 even)

  // Q fragments (B-operand: row=lane&15=q, slots hi*8+jj over d)
  f16x8 qf[2][4];
#pragma unroll
  for (int qb = 0; qb < 2; ++qb) {
    const f16* qrow =
        qkv + base + (tq0 + w * 32 + qb * 16 + lo) * 6144 + h * 128;
#pragma unroll
    for (int dc = 0; dc < 4; ++dc)
      qf[qb][dc] = *(const f16x8*)(qrow + dc * 32 + hi * 8);
  }

  // prologue stage tile 0 into buffer 0
#pragma unroll
  for (int i = 0; i < 4; ++i)
    gload16(qkv + base + (long)(i * 16 + krow) * 6144 + 2048 + h * 128 + kch * 8,
            &Ks[0][i * 2048 + tid * 8]);
#pragma unroll
  for (int i = 0; i < 4; ++i)
    gload16(vt + (long)bh * 262144 + (long)(i * 32 + vd) * 2048 + vch * 8,
            &Vs[0][i * 2048 + tid * 8]);
  __syncthreads();  // vmcnt(0) drain -> tile 0 resident

  f32x4 acc[2][8] = {};
  float m_run[2] = {-INFINITY, -INFINITY};
  float l_run[2] = {0.f, 0.f};

  int cur = 0;
  for (int it = 0; it < 32; ++it) {
    const int kt = it * 64;
    // ---- async stage of next tile into the other buffer ----
    if (it < 31) {
      const int ktn = kt + 64;
#pragma unroll
      for (int i = 0; i < 4; ++i)
        gload16(
            qkv + base + (long)(ktn + i * 16 + krow) * 6144 + 2048 + h * 128 + kch * 8,
            &Ks[cur ^ 1][i * 2048 + tid * 8]);
#pragma unroll
      for (int i = 0; i < 4; ++i)
        gload16(vt + (long)bh * 262144 + (long)(i * 32 + vd) * 2048 + ktn + vch * 8,
                &Vs[cur ^ 1][i * 2048 + tid * 8]);
    }

    // ---- S^T = mfma(K, Q): col=q(lane&15), row=key ----
    f32x4 sa[2][4] = {};
    __builtin_amdgcn_s_setprio(1);
#pragma unroll
    for (int kb = 0; kb < 4; ++kb) {
      const int row = kb * 16 + lo;
#pragma unroll
      for (int dc = 0; dc < 4; ++dc) {
        f16x8 kf =
            *(const f16x8*)&Ks[cur][row * 128 + (((dc * 4 + hi) ^ (lo & 7)) * 8)];
        sa[0][kb] = MFMA16(kf, qf[0][dc], sa[0][kb]);
        sa[1][kb] = MFMA16(kf, qf[1][dc], sa[1][kb]);
      }
    }
    __builtin_amdgcn_s_setprio(0);

    // ---- online softmax per qb (lane = one query; keys kb*16+hi*4+r) ----
    float sc[2];
#pragma unroll
    for (int qb = 0; qb < 2; ++qb) {
      float v_[4][4];
      float mx = -INFINITY;
#pragma unroll
      for (int kb = 0; kb < 4; ++kb)
#pragma unroll
        for (int r = 0; r < 4; ++r) {
          v_[kb][r] = sa[qb][kb][r] * isd;
          mx = fmaxf(mx, v_[kb][r]);
        }
      mx = fmaxf(mx, __shfl_xor(mx, 16));
      mx = fmaxf(mx, __shfl_xor(mx, 32));
      float mn = fmaxf(m_run[qb], mx);
      sc[qb] = __expf(m_run[qb] - mn);  // 0 on first tile
      m_run[qb] = mn;
      float sum = 0.f;
#pragma unroll
      for (int kb = 0; kb < 4; ++kb)
#pragma unroll
        for (int r = 0; r < 4; ++r) {
          v_[kb][r] = __expf(v_[kb][r] - mn);
          sum += v_[kb][r];
        }
      sum += __shfl_xor(sum, 16);
      sum += __shfl_xor(sum, 32);
      l_run[qb] = l_run[qb] * sc[qb] + sum;
      // P -> swizzled per-wave scratch (b64, conflict-free)
#pragma unroll
      for (int kb = 0; kb < 4; ++kb) {
        f16x4 pk = {(f16)v_[kb][0], (f16)v_[kb][1], (f16)v_[kb][2],
                    (f16)v_[kb][3]};
        *(f16x4*)&Pl[w][qb][lo * 64 + ((kb * 16 + hi * 4) ^ ((lo & 7) * 8))] = pk;
      }
    }
    asm volatile("s_waitcnt lgkmcnt(0)" ::: "memory");
    __builtin_amdgcn_sched_barrier(0);

    // reload P as B-operand frags: row=q, slots hi*8+jj = keys c*32+hi*8+jj
    f16x8 pf[2][2];
#pragma unroll
    for (int qb = 0; qb < 2; ++qb)
#pragma unroll
      for (int c = 0; c < 2; ++c)
        pf[qb][c] =
            *(const f16x8*)&Pl[w][qb][lo * 64 + ((c * 32 + hi * 8) ^ ((lo & 7) * 8))];

    // rescale running O^T by exp(m_old - m_new)
#pragma unroll
    for (int qb = 0; qb < 2; ++qb)
#pragma unroll
      for (int dg = 0; dg < 8; ++dg)
#pragma unroll
        for (int r = 0; r < 4; ++r) acc[qb][dg][r] *= sc[qb];

    // ---- O^T += mfma(V^T, P): col=q, row=d ----
    __builtin_amdgcn_s_setprio(1);
#pragma unroll
    for (int dg = 0; dg < 8; ++dg) {
      const int d = dg * 16 + lo;
#pragma unroll
      for (int c = 0; c < 2; ++c) {
        f16x8 vf = *(const f16x8*)&Vs[cur][d * 64 + (((c * 4 + hi) ^ (lo & 7)) * 8)];
        acc[0][dg] = MFMA16(vf, pf[0][c], acc[0][dg]);
        acc[1][dg] = MFMA16(vf, pf[1][c], acc[1][dg]);
      }
    }
    __builtin_amdgcn_s_setprio(0);

    __syncthreads();  // drains vmcnt(0): next tile resident; cur free
    cur ^= 1;
  }

  // epilogue: normalize + store y[b][t][h][d] (t = tq0+w*32+qb*16+lo)
#pragma unroll
  for (int qb = 0; qb < 2; ++qb) {
    float inv = 1.0f / l_run[qb];
    long t = tq0 + w * 32 + qb * 16 + lo;
    f16* yr = y + ((b * 2048 + t) * 16 + h) * 128;
#pragma unroll
    for (int dg = 0; dg < 8; ++dg) {
      f16x4 o = {(f16)(acc[qb][dg][0] * inv), (f16)(acc[qb][dg][1] * inv),
                 (f16)(acc[qb][dg][2] * inv), (f16)(acc[qb][dg][3] * inv)};
      *(f16x4*)&yr[dg * 16 + hi * 4] = o;
    }
  }
}

// ---------------------------------------------------------------------------
// ws layout (f16): x_h | wqkv_h | wproj_h | qkv_h | vt | y_h  = 224 MB
// ---------------------------------------------------------------------------
extern "C" void kernel_launch(void* const* d_in, const int* in_sizes, int n_in,
                              void* d_out, int out_size, void* d_ws,
                              size_t ws_size, hipStream_t stream) {
  const float* x = (const float*)d_in[0];
  const float* cosb = (const float*)d_in[1];
  const float* sinb = (const float*)d_in[2];
  const float* w_qkv = (const float*)d_in[3];
  const float* w_proj = (const float*)d_in[4];
  const float* g_q = (const float*)d_in[5];
  const float* g_k = (const float*)d_in[6];
  float* out = (float*)d_out;

  f16* ws = (f16*)d_ws;
  f16* x_h = ws;                     // 16777216
  f16* wqkv_h = x_h + 16777216;      // 12582912
  f16* wproj_h = wqkv_h + 12582912;  // 4194304
  f16* qkv_h = wproj_h + 4194304;    // 50331648
  f16* vt_h = qkv_h + 50331648;      // 16777216
  f16* y_h = vt_h + 16777216;        // 16777216

  cvt_f16<<<2048, 256, 0, stream>>>(x, x_h, 16777216 / 4);
  cvt_f16<<<2048, 256, 0, stream>>>(w_qkv, wqkv_h, 12582912 / 4);
  cvt_f16<<<1024, 256, 0, stream>>>(w_proj, wproj_h, 4194304 / 4);

  // qkv = x @ w_qkv^T : M=8192, N=6144, K=2048
  gemm_f16<f16><<<dim3(48, 64), 256, 0, stream>>>(x_h, wqkv_h, qkv_h, 8192,
                                                  6144, 2048);
  rope_f16<<<65536, 256, 0, stream>>>(qkv_h, cosb, sinb, g_q, g_k);
  transpose_v<<<2048, 256, 0, stream>>>(qkv_h, vt_h);
  attn_f16<<<1024, 256, 0, stream>>>(qkv_h, vt_h, y_h);
  // out = y @ w_proj^T : M=8192, N=2048, K=2048 (f32 out)
  gemm_f16<float><<<dim3(16, 64), 256, 0, stream>>>(y_h, wproj_h, out, 8192,
                                                    2048, 2048);
}